// Round 2
// baseline (237.012 us; speedup 1.0000x reference)
//
#include <hip/hip_runtime.h>
#include <hip/hip_bf16.h>

#define NN 8192
#define IND 512
#define OUTD 64
#define ALPHA_ 0.2f
#define LOG2E 1.4426950408889634f

typedef float f32x4 __attribute__((ext_vector_type(4)));
typedef short s16x8 __attribute__((ext_vector_type(8)));
typedef int   i32x4 __attribute__((ext_vector_type(4)));

static __device__ __forceinline__ short f2bf(float x) {
    __hip_bfloat16 b = __float2bfloat16(x);
    return *reinterpret_cast<short*>(&b);
}

// ---- kernel 0: transpose W [512][64] -> WT [64][512] (f32) ----
__global__ __launch_bounds__(256) void k_transposeW(const float* __restrict__ W,
                                                    float* __restrict__ WT) {
    int idx = blockIdx.x * 256 + threadIdx.x;   // 32768 elements
    int k = idx >> 6, c = idx & 63;
    WT[c * IND + k] = W[idx];
}

// ---- kernel 1: Wh = h@W per row; also Wh1=Wh@a1, Wh2=Wh@a2, WhT bf16 [64][8192] ----
__global__ __launch_bounds__(256) void k_wh(const float* __restrict__ h,
                                            const float* __restrict__ WT,
                                            const float* __restrict__ a,
                                            __hip_bfloat16* __restrict__ whT,
                                            float* __restrict__ Wh1,
                                            float* __restrict__ Wh2) {
    __shared__ float hs[4 * IND];
    int tid = threadIdx.x;
    const f32x4* h4 = (const f32x4*)(h + (size_t)blockIdx.x * 4 * IND);
    f32x4* hs4 = (f32x4*)hs;
    hs4[tid] = h4[tid];
    hs4[tid + 256] = h4[tid + 256];
    __syncthreads();

    int r = tid >> 6, c = tid & 63;            // one wave == one row, lane == out col
    int row = blockIdx.x * 4 + r;
    const f32x4* hv4 = (const f32x4*)(hs + r * IND);
    const f32x4* wv4 = (const f32x4*)(WT + (size_t)c * IND);
    float acc = 0.f;
    #pragma unroll 4
    for (int k4 = 0; k4 < IND / 4; ++k4) {
        f32x4 hv = hv4[k4];
        f32x4 wv = wv4[k4];
        acc = fmaf(hv[0], wv[0], acc);
        acc = fmaf(hv[1], wv[1], acc);
        acc = fmaf(hv[2], wv[2], acc);
        acc = fmaf(hv[3], wv[3], acc);
    }
    whT[(size_t)c * NN + row] = __float2bfloat16(acc);

    float v1 = acc * a[c];
    float v2 = acc * a[OUTD + c];
    #pragma unroll
    for (int off = 1; off < 64; off <<= 1) {
        v1 += __shfl_xor(v1, off, 64);
        v2 += __shfl_xor(v2, off, 64);
    }
    if (c == 0) { Wh1[row] = v1; Wh2[row] = v2; }
}

// ---- kernel 1b: mx = max_j Wh2[j] ----
__global__ __launch_bounds__(256) void k_max(const float* __restrict__ Wh2,
                                             float* __restrict__ mx) {
    float m = -1e30f;
    for (int i = threadIdx.x; i < NN; i += 256) m = fmaxf(m, Wh2[i]);
    #pragma unroll
    for (int off = 1; off < 64; off <<= 1) m = fmaxf(m, __shfl_xor(m, off, 64));
    __shared__ float sm[4];
    if ((threadIdx.x & 63) == 0) sm[threadIdx.x >> 6] = m;
    __syncthreads();
    if (threadIdx.x == 0) *mx = fmaxf(fmaxf(sm[0], sm[1]), fmaxf(sm[2], sm[3]));
}

// ---- kernel 2: fused mask+softmax+PV. 16 rows/block, 4 waves split the j range. ----
__global__ __launch_bounds__(256) void k_gat(const int* __restrict__ adj,
                                             const __hip_bfloat16* __restrict__ whT,
                                             const float* __restrict__ Wh1,
                                             const float* __restrict__ Wh2,
                                             const float* __restrict__ mxp,
                                             float* __restrict__ out) {
    int tid = threadIdx.x;
    int w   = tid >> 6;        // wave 0..3
    int l   = tid & 63;
    int lr  = l & 15;          // A-row / B-col within 16-tile
    int grp = l >> 4;          // k-group (8 consecutive j per lane)
    int ib  = blockIdx.x * 16;
    int row = ib + lr;

    float wh1r = Wh1[row];
    float mi = wh1r + *mxp;            // upper bound on row max of e (leakyrelu monotone)
    mi = fmaxf(mi, ALPHA_ * mi);
    float mc = mi * LOG2E;

    f32x4 acc0 = {0.f, 0.f, 0.f, 0.f};
    f32x4 acc1 = acc0, acc2 = acc0, acc3 = acc0;
    float lsum = 0.f;

    const int* ap = adj + (size_t)row * NN;
    const __hip_bfloat16* bp = whT + (size_t)lr * NN;

    for (int it = 0; it < 64; ++it) {
        int jl = it * 128 + w * 32 + grp * 8;
        i32x4 av0 = *(const i32x4*)(ap + jl);
        i32x4 av1 = *(const i32x4*)(ap + jl + 4);
        f32x4 w20 = *(const f32x4*)(Wh2 + jl);
        f32x4 w21 = *(const f32x4*)(Wh2 + jl + 4);
        s16x8 b0 = *(const s16x8*)(bp + jl);
        s16x8 b1 = *(const s16x8*)(bp + (size_t)16 * NN + jl);
        s16x8 b2 = *(const s16x8*)(bp + (size_t)32 * NN + jl);
        s16x8 b3 = *(const s16x8*)(bp + (size_t)48 * NN + jl);

        s16x8 af;
        #pragma unroll
        for (int e = 0; e < 4; ++e) {
            float x = wh1r + w20[e];
            x = fmaxf(x, ALPHA_ * x);                  // leaky relu
            float p = exp2f(fmaf(x, LOG2E, -mc));      // exp(x - mi)
            p = (av0[e] > 0) ? p : 0.f;                // adjacency mask
            lsum += p;
            af[e] = f2bf(p);
        }
        #pragma unroll
        for (int e = 0; e < 4; ++e) {
            float x = wh1r + w21[e];
            x = fmaxf(x, ALPHA_ * x);
            float p = exp2f(fmaf(x, LOG2E, -mc));
            p = (av1[e] > 0) ? p : 0.f;
            lsum += p;
            af[e + 4] = f2bf(p);
        }
        acc0 = __builtin_amdgcn_mfma_f32_16x16x32_bf16(af, b0, acc0, 0, 0, 0);
        acc1 = __builtin_amdgcn_mfma_f32_16x16x32_bf16(af, b1, acc1, 0, 0, 0);
        acc2 = __builtin_amdgcn_mfma_f32_16x16x32_bf16(af, b2, acc2, 0, 0, 0);
        acc3 = __builtin_amdgcn_mfma_f32_16x16x32_bf16(af, b3, acc3, 0, 0, 0);
    }

    // denominator: sum across the 4 k-groups (lanes xor 16/32)
    lsum += __shfl_xor(lsum, 16, 64);
    lsum += __shfl_xor(lsum, 32, 64);

    // cross-wave combine via LDS
    __shared__ float lacc[4][16][65];
    __shared__ float lls[4][16];
    #pragma unroll
    for (int reg = 0; reg < 4; ++reg) {
        int rr = grp * 4 + reg;           // C layout: row=(lane>>4)*4+reg, col=lane&15
        lacc[w][rr][lr]      = acc0[reg];
        lacc[w][rr][16 + lr] = acc1[reg];
        lacc[w][rr][32 + lr] = acc2[reg];
        lacc[w][rr][48 + lr] = acc3[reg];
    }
    if (l < 16) lls[w][l] = lsum;
    __syncthreads();

    #pragma unroll
    for (int t = 0; t < 4; ++t) {
        int idx = tid + t * 256;          // 1024 outputs: 16 rows x 64 cols
        int rr = idx >> 6, c = idx & 63;
        float v  = lacc[0][rr][c] + lacc[1][rr][c] + lacc[2][rr][c] + lacc[3][rr][c];
        float ls = lls[0][rr] + lls[1][rr] + lls[2][rr] + lls[3][rr];
        float hv = v / ls;
        out[(size_t)(ib + rr) * OUTD + c] = hv > 0.f ? hv : exp2f(hv * LOG2E) - 1.f;
    }
}

extern "C" void kernel_launch(void* const* d_in, const int* in_sizes, int n_in,
                              void* d_out, int out_size, void* d_ws, size_t ws_size,
                              hipStream_t stream) {
    const float* h   = (const float*)d_in[0];
    const int*   adj = (const int*)d_in[1];
    const float* W   = (const float*)d_in[2];
    const float* a   = (const float*)d_in[3];
    float* out = (float*)d_out;

    char* ws = (char*)d_ws;
    float*           WT  = (float*)ws;                               // 128 KB
    __hip_bfloat16*  whT = (__hip_bfloat16*)(ws + 131072);           // 1 MB
    float*           Wh1 = (float*)(ws + 131072 + 1048576);          // 32 KB
    float*           Wh2 = Wh1 + NN;                                 // 32 KB
    float*           mx  = Wh2 + NN;                                 // 4 B

    k_transposeW<<<(IND * OUTD) / 256, 256, 0, stream>>>(W, WT);
    k_wh<<<NN / 4, 256, 0, stream>>>(h, WT, a, whT, Wh1, Wh2);
    k_max<<<1, 256, 0, stream>>>(Wh2, mx);
    k_gat<<<NN / 16, 256, 0, stream>>>(adj, whT, Wh1, Wh2, mx, out);
}

// Round 3
// 132.852 us; speedup vs baseline: 1.7840x; 1.7840x over previous
//
#include <hip/hip_runtime.h>
#include <hip/hip_bf16.h>

#define NN 8192
#define IND 512
#define OUTD 64
#define ALPHA_ 0.2f
#define LOG2E 1.4426950408889634f

typedef float f32x4 __attribute__((ext_vector_type(4)));
typedef short s16x8 __attribute__((ext_vector_type(8)));
typedef int   i32x4 __attribute__((ext_vector_type(4)));

static __device__ __forceinline__ short f2bf(float x) {
    __hip_bfloat16 b = __float2bfloat16(x);
    return *reinterpret_cast<short*>(&b);
}

// ---- kernel 1: Wh = h@W; Wh1=Wh@a1, Wh2=Wh@a2, whT bf16 [64][8192] ----
// 8 rows/block, 4 waves; wave w owns rows w*2..w*2+1.
// Lane layout: g = lane>>4 (k-group), lc = lane&15 (4 cols each).
// W loads are fully coalesced: per inst, 64 lanes cover 1KB contiguous.
__global__ __launch_bounds__(256) void k_wh(const float* __restrict__ h,
                                            const float* __restrict__ W,
                                            const float* __restrict__ a,
                                            __hip_bfloat16* __restrict__ whT,
                                            float* __restrict__ Wh1,
                                            float* __restrict__ Wh2) {
    __shared__ float hs[8 * IND];      // 16 KB
    int tid = threadIdx.x;
    const f32x4* h4 = (const f32x4*)(h + (size_t)blockIdx.x * 8 * IND);
    f32x4* hs4 = (f32x4*)hs;
    #pragma unroll
    for (int t = 0; t < 4; ++t) hs4[tid + t * 256] = h4[tid + t * 256];
    __syncthreads();

    int w = tid >> 6, l = tid & 63;
    int g = l >> 4, lc = l & 15;
    int c4 = lc * 4;
    const float* hrow = hs + (w * 2) * IND;
    f32x4 acc0 = {0.f, 0.f, 0.f, 0.f};
    f32x4 acc1 = {0.f, 0.f, 0.f, 0.f};

    #pragma unroll 4
    for (int k0 = 0; k0 < 128; ++k0) {
        int k = k0 * 4 + g;
        f32x4 wv = *(const f32x4*)(W + k * OUTD + c4);
        float h0 = hrow[k];
        float h1 = hrow[IND + k];
        acc0[0] = fmaf(h0, wv[0], acc0[0]);
        acc0[1] = fmaf(h0, wv[1], acc0[1]);
        acc0[2] = fmaf(h0, wv[2], acc0[2]);
        acc0[3] = fmaf(h0, wv[3], acc0[3]);
        acc1[0] = fmaf(h1, wv[0], acc1[0]);
        acc1[1] = fmaf(h1, wv[1], acc1[1]);
        acc1[2] = fmaf(h1, wv[2], acc1[2]);
        acc1[3] = fmaf(h1, wv[3], acc1[3]);
    }

    // reduce across the 4 k-groups (lanes xor 16, 32)
    #pragma unroll
    for (int e = 0; e < 4; ++e) {
        acc0[e] += __shfl_xor(acc0[e], 16, 64);
        acc0[e] += __shfl_xor(acc0[e], 32, 64);
        acc1[e] += __shfl_xor(acc1[e], 16, 64);
        acc1[e] += __shfl_xor(acc1[e], 32, 64);
    }

    int row0 = blockIdx.x * 8 + w * 2;
    if (g == 0) {
        #pragma unroll
        for (int e = 0; e < 4; ++e) {
            whT[(size_t)(c4 + e) * NN + row0]     = __float2bfloat16(acc0[e]);
            whT[(size_t)(c4 + e) * NN + row0 + 1] = __float2bfloat16(acc1[e]);
        }
    }

    float p10 = 0.f, p20 = 0.f, p11 = 0.f, p21 = 0.f;
    #pragma unroll
    for (int e = 0; e < 4; ++e) {
        float a1 = a[c4 + e], a2 = a[OUTD + c4 + e];
        p10 = fmaf(acc0[e], a1, p10);
        p20 = fmaf(acc0[e], a2, p20);
        p11 = fmaf(acc1[e], a1, p11);
        p21 = fmaf(acc1[e], a2, p21);
    }
    #pragma unroll
    for (int off = 1; off < 16; off <<= 1) {
        p10 += __shfl_xor(p10, off, 64);
        p20 += __shfl_xor(p20, off, 64);
        p11 += __shfl_xor(p11, off, 64);
        p21 += __shfl_xor(p21, off, 64);
    }
    if (l == 0) {
        Wh1[row0] = p10;     Wh2[row0] = p20;
        Wh1[row0 + 1] = p11; Wh2[row0 + 1] = p21;
    }
}

// ---- kernel 1b: mx = max_j Wh2[j] ----
__global__ __launch_bounds__(256) void k_max(const float* __restrict__ Wh2,
                                             float* __restrict__ mx) {
    float m = -1e30f;
    for (int i = threadIdx.x; i < NN; i += 256) m = fmaxf(m, Wh2[i]);
    #pragma unroll
    for (int off = 1; off < 64; off <<= 1) m = fmaxf(m, __shfl_xor(m, off, 64));
    __shared__ float sm[4];
    if ((threadIdx.x & 63) == 0) sm[threadIdx.x >> 6] = m;
    __syncthreads();
    if (threadIdx.x == 0) *mx = fmaxf(fmaxf(sm[0], sm[1]), fmaxf(sm[2], sm[3]));
}

// ---- kernel 2: fused mask+softmax+PV. 16 rows/block, 8 waves split j. ----
__global__ __launch_bounds__(512) void k_gat(const int* __restrict__ adj,
                                             const __hip_bfloat16* __restrict__ whT,
                                             const float* __restrict__ Wh1,
                                             const float* __restrict__ Wh2,
                                             const float* __restrict__ mxp,
                                             float* __restrict__ out) {
    int tid = threadIdx.x;
    int w   = tid >> 6;        // wave 0..7
    int l   = tid & 63;
    int lr  = l & 15;          // A-row / B-col within 16-tile
    int grp = l >> 4;          // k-group (8 consecutive j per lane)
    int ib  = blockIdx.x * 16;
    int row = ib + lr;

    float wh1r = Wh1[row];
    float mi = wh1r + *mxp;            // upper bound on row max of e (leakyrelu monotone)
    mi = fmaxf(mi, ALPHA_ * mi);
    float mc = mi * LOG2E;

    f32x4 acc0 = {0.f, 0.f, 0.f, 0.f};
    f32x4 acc1 = acc0, acc2 = acc0, acc3 = acc0;
    float lsum = 0.f;

    const int* ap = adj + (size_t)row * NN;
    const __hip_bfloat16* bp = whT + (size_t)lr * NN;
    int jbase = w * 32 + grp * 8;

#define LOADJ(J, AV0, AV1, W20, W21, B0, B1, B2, B3)           \
    AV0 = *(const i32x4*)(ap + (J));                           \
    AV1 = *(const i32x4*)(ap + (J) + 4);                       \
    W20 = *(const f32x4*)(Wh2 + (J));                          \
    W21 = *(const f32x4*)(Wh2 + (J) + 4);                      \
    B0  = *(const s16x8*)(bp + (J));                           \
    B1  = *(const s16x8*)(bp + (size_t)16 * NN + (J));         \
    B2  = *(const s16x8*)(bp + (size_t)32 * NN + (J));         \
    B3  = *(const s16x8*)(bp + (size_t)48 * NN + (J));

    i32x4 av0, av1;
    f32x4 w20, w21;
    s16x8 b0, b1, b2, b3;
    LOADJ(jbase, av0, av1, w20, w21, b0, b1, b2, b3)

    for (int it = 0; it < 32; ++it) {
        i32x4 nav0, nav1;
        f32x4 nw20, nw21;
        s16x8 nb0, nb1, nb2, nb3;
        if (it < 31) {
            int jn = (it + 1) * 256 + jbase;
            LOADJ(jn, nav0, nav1, nw20, nw21, nb0, nb1, nb2, nb3)
        }

        s16x8 af;
        #pragma unroll
        for (int e = 0; e < 4; ++e) {
            float x = wh1r + w20[e];
            x = fmaxf(x, ALPHA_ * x);                  // leaky relu
            float p = exp2f(fmaf(x, LOG2E, -mc));      // exp(x - mi)
            p = (av0[e] > 0) ? p : 0.f;                // adjacency mask
            lsum += p;
            af[e] = f2bf(p);
        }
        #pragma unroll
        for (int e = 0; e < 4; ++e) {
            float x = wh1r + w21[e];
            x = fmaxf(x, ALPHA_ * x);
            float p = exp2f(fmaf(x, LOG2E, -mc));
            p = (av1[e] > 0) ? p : 0.f;
            lsum += p;
            af[e + 4] = f2bf(p);
        }
        acc0 = __builtin_amdgcn_mfma_f32_16x16x32_bf16(af, b0, acc0, 0, 0, 0);
        acc1 = __builtin_amdgcn_mfma_f32_16x16x32_bf16(af, b1, acc1, 0, 0, 0);
        acc2 = __builtin_amdgcn_mfma_f32_16x16x32_bf16(af, b2, acc2, 0, 0, 0);
        acc3 = __builtin_amdgcn_mfma_f32_16x16x32_bf16(af, b3, acc3, 0, 0, 0);

        if (it < 31) {
            av0 = nav0; av1 = nav1;
            w20 = nw20; w21 = nw21;
            b0 = nb0; b1 = nb1; b2 = nb2; b3 = nb3;
        }
    }
#undef LOADJ

    // denominator: sum across the 4 k-groups (lanes xor 16/32)
    lsum += __shfl_xor(lsum, 16, 64);
    lsum += __shfl_xor(lsum, 32, 64);

    // cross-wave combine via LDS
    __shared__ float lacc[8][16][65];
    __shared__ float lls[8][16];
    #pragma unroll
    for (int reg = 0; reg < 4; ++reg) {
        int rr = grp * 4 + reg;           // C layout: row=(lane>>4)*4+reg, col=lane&15
        lacc[w][rr][lr]      = acc0[reg];
        lacc[w][rr][16 + lr] = acc1[reg];
        lacc[w][rr][32 + lr] = acc2[reg];
        lacc[w][rr][48 + lr] = acc3[reg];
    }
    if (l < 16) lls[w][l] = lsum;
    __syncthreads();

    #pragma unroll
    for (int t = 0; t < 2; ++t) {
        int idx = tid + t * 512;          // 1024 outputs: 16 rows x 64 cols
        int rr = idx >> 6, c = idx & 63;
        float v = 0.f, ls = 0.f;
        #pragma unroll
        for (int ww = 0; ww < 8; ++ww) {
            v += lacc[ww][rr][c];
            ls += lls[ww][rr];
        }
        float hv = v / ls;
        out[(size_t)(ib + rr) * OUTD + c] = hv > 0.f ? hv : exp2f(hv * LOG2E) - 1.f;
    }
}

extern "C" void kernel_launch(void* const* d_in, const int* in_sizes, int n_in,
                              void* d_out, int out_size, void* d_ws, size_t ws_size,
                              hipStream_t stream) {
    const float* h   = (const float*)d_in[0];
    const int*   adj = (const int*)d_in[1];
    const float* W   = (const float*)d_in[2];
    const float* a   = (const float*)d_in[3];
    float* out = (float*)d_out;

    char* ws = (char*)d_ws;
    __hip_bfloat16*  whT = (__hip_bfloat16*)ws;                      // 1 MB
    float*           Wh1 = (float*)(ws + 1048576);                   // 32 KB
    float*           Wh2 = Wh1 + NN;                                 // 32 KB
    float*           mx  = Wh2 + NN;                                 // 4 B

    k_wh<<<NN / 8, 256, 0, stream>>>(h, W, a, whT, Wh1, Wh2);
    k_max<<<1, 256, 0, stream>>>(Wh2, mx);
    k_gat<<<NN / 16, 512, 0, stream>>>(adj, whT, Wh1, Wh2, mx, out);
}